// Round 3
// baseline (1981.598 us; speedup 1.0000x reference)
//
#include <hip/hip_runtime.h>
#include <hip/hip_cooperative_groups.h>

namespace cg = cooperative_groups;

#define BATCH 32768
#define TT 11
#define EE 128
#define HH 20

// ws layout (bytes):
//   [0 .. 8192)              : double slots[1024]
//       step t stats: slots[t*64 + j]=sum_j, slots[t*64+20+j]=sumsq_j; loss=slots[704], acc=slots[705]
//   [8192 .. +28835840)      : float zc  [T][H][B]
//   [+.. ]                   : float hist[T][H][B]  (fallback path only)
//   [+.. ]                   : float hs  [H][B]     (fallback path only)
#define ZC_OFF   8192
#define HIST_OFF (8192 + 28835840)
#define HS_OFF   (8192 + 2*28835840)

__device__ __forceinline__ float waveRed(float v) {
    #pragma unroll
    for (int m = 32; m > 0; m >>= 1) v += __shfl_xor(v, m, 64);
    return v;
}

// ---------------- Kernel A: per-(b,t) input MLP -> zc[t][j][b]; block 0 zeroes slots ----------------
// LDS only for s1 (25.6 KB -> 6 blocks/CU). z is computed in 20-wide register chunks and
// immediately folded into zcr (static indices everywhere -> no scratch, no z staging).
__global__ __launch_bounds__(128) void mlp_kernel(
    const float* __restrict__ bx, const float* __restrict__ w1, const float* __restrict__ b1,
    const float* __restrict__ w2, const float* __restrict__ b2,
    const float* __restrict__ c,
    float* __restrict__ zc, double* __restrict__ slots)
{
    __shared__ float s1s[50 * 128];   // 25.6 KB
    const int tid = threadIdx.x;
    if (blockIdx.x == 0) {
        for (int i = tid; i < 1024; i += 128) slots[i] = 0.0;   // later kernels are stream-ordered
    }
    const int gid = blockIdx.x * 128 + tid;
    const int t = gid >> 15;
    const int b = gid & (BATCH - 1);
    const float* xp = bx + ((size_t)b * TT + t) * EE;

    // phase 1: s1[50] = relu(x @ w1 + b1); x as float4, w1 rows are wave-uniform (scalar loads)
    float s1r[50];
    #pragma unroll
    for (int k = 0; k < 50; ++k) s1r[k] = b1[k];
    #pragma unroll 4
    for (int e4 = 0; e4 < 32; ++e4) {
        const float4 xv = *(const float4*)(xp + e4 * 4);
        const float* wr = w1 + e4 * 200;
        #pragma unroll
        for (int k = 0; k < 50; ++k) s1r[k] = fmaf(xv.x, wr[k], s1r[k]);
        #pragma unroll
        for (int k = 0; k < 50; ++k) s1r[k] = fmaf(xv.y, wr[50 + k], s1r[k]);
        #pragma unroll
        for (int k = 0; k < 50; ++k) s1r[k] = fmaf(xv.z, wr[100 + k], s1r[k]);
        #pragma unroll
        for (int k = 0; k < 50; ++k) s1r[k] = fmaf(xv.w, wr[150 + k], s1r[k]);
    }
    #pragma unroll
    for (int k = 0; k < 50; ++k) s1s[k * 128 + tid] = fmaxf(s1r[k], 0.f);
    // own-column LDS use only -> no __syncthreads needed

    // phases 2+3 fused: for each 20-wide z chunk: za = relu(s1 @ w2[:,chunk] + b2[chunk]);
    // zcr += za @ c[chunk,:]
    float zcr[HH];
    #pragma unroll
    for (int j = 0; j < HH; ++j) zcr[j] = 0.f;
    #pragma unroll
    for (int c5 = 0; c5 < 5; ++c5) {
        const int base = c5 * 20;
        float za[20];
        #pragma unroll
        for (int k = 0; k < 20; ++k) za[k] = b2[base + k];
        for (int f = 0; f < 50; ++f) {                  // rolled; s1 via stride-1 LDS (conflict-free)
            const float sv = s1s[f * 128 + tid];
            const float* wr = w2 + f * 100 + base;      // wave-uniform -> s_load
            #pragma unroll
            for (int k = 0; k < 20; ++k) za[k] = fmaf(sv, wr[k], za[k]);
        }
        #pragma unroll
        for (int k = 0; k < 20; ++k) {
            const float zv = fmaxf(za[k], 0.f);
            const float* cr = c + (base + k) * HH;      // wave-uniform -> s_load
            #pragma unroll
            for (int j = 0; j < HH; ++j) zcr[j] = fmaf(zv, cr[j], zcr[j]);
        }
    }
    #pragma unroll
    for (int j = 0; j < HH; ++j) zc[((size_t)(t * HH + j) << 15) + b] = zcr[j];
}

// ---------------- Kernel B: cooperative persistent scan + head + loss ----------------
// 512 blocks x 64 threads (1 wave/block), 56.3 KB static LDS -> 2 blocks/CU co-resident.
__global__ __launch_bounds__(64) void scan_coop(
    const float* __restrict__ zc, const float* __restrict__ by,
    const float* __restrict__ lp, const float* __restrict__ ep,
    const float* __restrict__ w,  const float* __restrict__ g, const float* __restrict__ bb,
    const float* __restrict__ w3, const float* __restrict__ b3,
    const float* __restrict__ w4, const float* __restrict__ b4,
    double* __restrict__ slots, float* __restrict__ out)
{
    __shared__ float lmem[TT * HH * 64];   // 56320 B: scan hist; reused as hf staging in head
    cg::grid_group grid = cg::this_grid();
    const int tid = threadIdx.x;           // lane (block == one wave)
    const int b = blockIdx.x * 64 + tid;
    const float l0 = lp[0], e0 = ep[0];

    float h[HH], hs[HH];
    #pragma unroll
    for (int j = 0; j < HH; ++j) h[j] = 0.f;

    #pragma unroll 1
    for (int t = 0; t < TT; ++t) {
        float zct[HH], hn[HH];
        #pragma unroll
        for (int j = 0; j < HH; ++j) zct[j] = zc[((t * HH + j) << 15) + b];

        // hn = relu(h @ w + zc_t)
        #pragma unroll
        for (int j = 0; j < HH; ++j) {
            float a = zct[j];
            #pragma unroll
            for (int i = 0; i < HH; ++i) a = fmaf(h[i], w[i * HH + j], a);
            hn[j] = fmaxf(a, 0.f);
        }
        #pragma unroll
        for (int j = 0; j < HH; ++j) lmem[((t * HH + j) << 6) + tid] = hn[j];

        // pv = hn @ a_t = e * sum_{s<=t} l^(t-s) (hn . hn_s) hn_s
        float pv[HH];
        {
            float d = 0.f;
            #pragma unroll
            for (int j = 0; j < HH; ++j) d = fmaf(hn[j], hn[j], d);
            const float cd = e0 * d;
            #pragma unroll
            for (int j = 0; j < HH; ++j) pv[j] = cd * hn[j];
        }
        float coef = e0 * l0;
        #pragma unroll 1
        for (int s = t - 1; s >= 0; --s) {
            float tv[HH];
            #pragma unroll
            for (int j = 0; j < HH; ++j) tv[j] = lmem[((s * HH + j) << 6) + tid];
            float d = 0.f;
            #pragma unroll
            for (int j = 0; j < HH; ++j) d = fmaf(hn[j], tv[j], d);
            const float cd = coef * d;
            #pragma unroll
            for (int j = 0; j < HH; ++j) pv[j] = fmaf(cd, tv[j], pv[j]);
            coef *= l0;
        }

        // hs = hn @ w + zc_t + pv (pre-norm)
        #pragma unroll
        for (int j = 0; j < HH; ++j) {
            float a = zct[j] + pv[j];
            #pragma unroll
            for (int i = 0; i < HH; ++i) a = fmaf(hn[i], w[i * HH + j], a);
            hs[j] = a;
        }

        // per-channel batch stats: wave reduce, lane j / lane 20+j carry the atomic payload
        float redv = 0.f;
        #pragma unroll
        for (int j = 0; j < HH; ++j) {
            const float sm = waveRed(hs[j]);
            const float sq = waveRed(hs[j] * hs[j]);
            if (tid == j) redv = sm;
            if (tid == HH + j) redv = sq;
        }
        if (tid < 2 * HH) atomicAdd(&slots[t * 64 + tid], (double)redv);
        __threadfence();
        grid.sync();

        // batch-norm (fp64 stats) + relu -> carry
        #pragma unroll
        for (int j = 0; j < HH; ++j) {
            const double s1 = __hip_atomic_load(&slots[t * 64 + j],      __ATOMIC_RELAXED, __HIP_MEMORY_SCOPE_AGENT);
            const double s2 = __hip_atomic_load(&slots[t * 64 + HH + j], __ATOMIC_RELAXED, __HIP_MEMORY_SCOPE_AGENT);
            const double mu  = s1 * (1.0 / 32768.0);
            const double var = s2 * (1.0 / 32768.0) - mu * mu;
            const float muf  = (float)mu;
            const float rsig = 1.0f / sqrtf((float)var);
            h[j] = fmaxf(fmaf(g[j] * rsig, hs[j] - muf, bb[j]), 0.f);
        }
    }

    // ---- head: hf = relu(h @ w3 + b3) -> LDS; logits in 32-wide chunks with online softmax ----
    {
        float hf[100];
        #pragma unroll
        for (int k = 0; k < 100; ++k) hf[k] = b3[k];
        #pragma unroll
        for (int i = 0; i < HH; ++i) {
            const float hv = h[i];
            const float* wr = w3 + i * 100;
            #pragma unroll
            for (int k = 0; k < 100; ++k) hf[k] = fmaf(hv, wr[k], hf[k]);
        }
        #pragma unroll
        for (int k = 0; k < 100; ++k) lmem[(k << 6) + tid] = fmaxf(hf[k], 0.f);
    }

    float gm = -3.402823e38f, se = 0.f, dotby = 0.f, sumby = 0.f, bymax = -3.402823e38f;
    int am = 0, byam = 0;
    const float* byp = by + (size_t)b * EE;
    #pragma unroll 1
    for (int ch = 0; ch < 4; ++ch) {
        const int base = ch * 32;
        float lgc[32];
        #pragma unroll
        for (int u = 0; u < 32; ++u) lgc[u] = b4[base + u];
        for (int k = 0; k < 100; ++k) {
            const float hv = lmem[(k << 6) + tid];
            const float* wr = w4 + k * EE + base;       // wave-uniform -> s_load
            #pragma unroll
            for (int u = 0; u < 32; ++u) lgc[u] = fmaf(hv, wr[u], lgc[u]);
        }
        // first-max argmax + online logsumexp
        const float gmold = gm;
        #pragma unroll
        for (int u = 0; u < 32; ++u) { if (lgc[u] > gm) { gm = lgc[u]; am = base + u; } }
        se *= expf(gmold - gm);
        #pragma unroll
        for (int u = 0; u < 32; ++u) se += expf(lgc[u] - gm);
        // by: loss pieces + first-max argmax
        #pragma unroll
        for (int u4 = 0; u4 < 8; ++u4) {
            const float4 v = *(const float4*)(byp + base + u4 * 4);
            const int u = u4 * 4;
            if (v.x > bymax) { bymax = v.x; byam = base + u; }
            if (v.y > bymax) { bymax = v.y; byam = base + u + 1; }
            if (v.z > bymax) { bymax = v.z; byam = base + u + 2; }
            if (v.w > bymax) { bymax = v.w; byam = base + u + 3; }
            dotby = fmaf(v.x, lgc[u], dotby);
            dotby = fmaf(v.y, lgc[u + 1], dotby);
            dotby = fmaf(v.z, lgc[u + 2], dotby);
            dotby = fmaf(v.w, lgc[u + 3], dotby);
            sumby += v.x + v.y + v.z + v.w;
        }
    }
    const float loss_i = -dotby + (gm + logf(se)) * sumby;
    const float acc_i = (am == byam) ? 1.f : 0.f;

    const float ls = waveRed(loss_i);
    const float as = waveRed(acc_i);
    if (tid == 0) atomicAdd(&slots[704], (double)ls);
    if (tid == 1) atomicAdd(&slots[705], (double)as);
    __threadfence();
    grid.sync();
    if (b == 0) {
        const double L = __hip_atomic_load(&slots[704], __ATOMIC_RELAXED, __HIP_MEMORY_SCOPE_AGENT);
        const double A = __hip_atomic_load(&slots[705], __ATOMIC_RELAXED, __HIP_MEMORY_SCOPE_AGENT);
        out[0] = (float)(L * (1.0 / 32768.0));
        out[1] = (float)(A * (1.0 / 32768.0));
    }
}

// ================= Fallback path (R2, proven correct) =================
__global__ __launch_bounds__(128) void step_kernel(
    const float* __restrict__ zc, const float* __restrict__ lp, const float* __restrict__ ep,
    const float* __restrict__ w, const float* __restrict__ g, const float* __restrict__ bb,
    float* __restrict__ hist, float* __restrict__ hs_buf, double* __restrict__ slots, int t)
{
    __shared__ float red[2][40];
    const int tid = threadIdx.x;
    const int b = blockIdx.x * 128 + tid;
    const int lane = tid & 63, wv = tid >> 6;
    const float l0 = lp[0], e0 = ep[0];

    float h[HH];
    if (t == 0) {
        #pragma unroll
        for (int j = 0; j < HH; ++j) h[j] = 0.f;
    } else {
        #pragma unroll
        for (int j = 0; j < HH; ++j) {
            const double s1 = slots[(t - 1) * 64 + j];
            const double s2 = slots[(t - 1) * 64 + HH + j];
            const double mu = s1 * (1.0 / 32768.0);
            const double var = s2 * (1.0 / 32768.0) - mu * mu;
            const float muf = (float)mu;
            const float rsig = 1.0f / sqrtf((float)var);
            const float hv = hs_buf[(j << 15) + b];
            h[j] = fmaxf(fmaf(g[j] * rsig, hv - muf, bb[j]), 0.f);
        }
    }
    float zct[HH];
    #pragma unroll
    for (int j = 0; j < HH; ++j) zct[j] = zc[((t * HH + j) << 15) + b];
    float hn[HH];
    #pragma unroll
    for (int j = 0; j < HH; ++j) {
        float a = zct[j];
        #pragma unroll
        for (int i = 0; i < HH; ++i) a = fmaf(h[i], w[i * HH + j], a);
        hn[j] = fmaxf(a, 0.f);
    }
    #pragma unroll
    for (int j = 0; j < HH; ++j) hist[((t * HH + j) << 15) + b] = hn[j];
    float pv[HH];
    {
        float d = 0.f;
        #pragma unroll
        for (int j = 0; j < HH; ++j) d = fmaf(hn[j], hn[j], d);
        const float cd = e0 * d;
        #pragma unroll
        for (int j = 0; j < HH; ++j) pv[j] = cd * hn[j];
    }
    float coef = e0 * l0;
    for (int s = t - 1; s >= 0; --s) {
        float tv[HH];
        #pragma unroll
        for (int j = 0; j < HH; ++j) tv[j] = hist[((s * HH + j) << 15) + b];
        float d = 0.f;
        #pragma unroll
        for (int j = 0; j < HH; ++j) d = fmaf(hn[j], tv[j], d);
        const float cd = coef * d;
        #pragma unroll
        for (int j = 0; j < HH; ++j) pv[j] = fmaf(cd, tv[j], pv[j]);
        coef *= l0;
    }
    float hs[HH];
    #pragma unroll
    for (int j = 0; j < HH; ++j) {
        float a = zct[j] + pv[j];
        #pragma unroll
        for (int i = 0; i < HH; ++i) a = fmaf(hn[i], w[i * HH + j], a);
        hs[j] = a;
        hs_buf[(j << 15) + b] = a;
    }
    #pragma unroll
    for (int j = 0; j < HH; ++j) {
        const float sm = waveRed(hs[j]);
        const float sq = waveRed(hs[j] * hs[j]);
        if (lane == 0) { red[wv][j] = sm; red[wv][HH + j] = sq; }
    }
    __syncthreads();
    if (tid < 2 * HH) atomicAdd(&slots[t * 64 + tid], (double)(red[0][tid] + red[1][tid]));
}

__global__ __launch_bounds__(128) void head_kernel(
    const float* __restrict__ hs_buf, const float* __restrict__ by,
    const float* __restrict__ g, const float* __restrict__ bb,
    const float* __restrict__ w3, const float* __restrict__ b3,
    const float* __restrict__ w4, const float* __restrict__ b4,
    double* __restrict__ slots)
{
    __shared__ float stg[100 * 128];
    __shared__ float red[2][2];
    const int tid = threadIdx.x;
    const int b = blockIdx.x * 128 + tid;
    const int lane = tid & 63, wv = tid >> 6;
    float h[HH];
    #pragma unroll
    for (int j = 0; j < HH; ++j) {
        const double s1 = slots[10 * 64 + j];
        const double s2 = slots[10 * 64 + HH + j];
        const double mu = s1 * (1.0 / 32768.0);
        const double var = s2 * (1.0 / 32768.0) - mu * mu;
        const float muf = (float)mu;
        const float rsig = 1.0f / sqrtf((float)var);
        const float hv = hs_buf[(j << 15) + b];
        h[j] = fmaxf(fmaf(g[j] * rsig, hv - muf, bb[j]), 0.f);
    }
    float hf[100];
    #pragma unroll
    for (int k = 0; k < 100; ++k) hf[k] = b3[k];
    #pragma unroll
    for (int i = 0; i < HH; ++i) {
        const float hv = h[i];
        const float* wr = w3 + i * 100;
        #pragma unroll
        for (int k = 0; k < 100; ++k) hf[k] = fmaf(hv, wr[k], hf[k]);
    }
    #pragma unroll
    for (int k = 0; k < 100; ++k) stg[k * 128 + tid] = fmaxf(hf[k], 0.f);
    float lg[EE];
    #pragma unroll
    for (int e = 0; e < EE; ++e) lg[e] = b4[e];
    for (int k = 0; k < 100; ++k) {
        const float hv = stg[k * 128 + tid];
        const float* wr = w4 + k * EE;
        #pragma unroll
        for (int e = 0; e < EE; ++e) lg[e] = fmaf(hv, wr[e], lg[e]);
    }
    float mx = lg[0]; int am = 0;
    #pragma unroll
    for (int e = 1; e < EE; ++e) { if (lg[e] > mx) { mx = lg[e]; am = e; } }
    float se = 0.f;
    #pragma unroll
    for (int e = 0; e < EE; ++e) se += expf(lg[e] - mx);
    const float lse = logf(se);
    const float* byp = by + (size_t)b * EE;
    float loss = 0.f, bymax = -3.402823e38f; int byam = 0;
    #pragma unroll
    for (int e4 = 0; e4 < 32; ++e4) {
        const float4 v = *(const float4*)(byp + e4 * 4);
        const int e = e4 * 4;
        if (v.x > bymax) { bymax = v.x; byam = e; }
        if (v.y > bymax) { bymax = v.y; byam = e + 1; }
        if (v.z > bymax) { bymax = v.z; byam = e + 2; }
        if (v.w > bymax) { bymax = v.w; byam = e + 3; }
        loss = fmaf(-v.x, lg[e] - mx - lse, loss);
        loss = fmaf(-v.y, lg[e + 1] - mx - lse, loss);
        loss = fmaf(-v.z, lg[e + 2] - mx - lse, loss);
        loss = fmaf(-v.w, lg[e + 3] - mx - lse, loss);
    }
    const float acc_i = (am == byam) ? 1.f : 0.f;
    const float ls = waveRed(loss);
    const float as = waveRed(acc_i);
    if (lane == 0) { red[wv][0] = ls; red[wv][1] = as; }
    __syncthreads();
    if (tid == 0) atomicAdd(&slots[704], (double)(red[0][0] + red[1][0]));
    if (tid == 1) atomicAdd(&slots[705], (double)(red[0][1] + red[1][1]));
}

__global__ void finalize_kernel(const double* __restrict__ slots, float* __restrict__ out) {
    out[0] = (float)(slots[704] * (1.0 / 32768.0));
    out[1] = (float)(slots[705] * (1.0 / 32768.0));
}

extern "C" void kernel_launch(void* const* d_in, const int* in_sizes, int n_in,
                              void* d_out, int out_size, void* d_ws, size_t ws_size,
                              hipStream_t stream) {
    const float* bx = (const float*)d_in[0];
    const float* by = (const float*)d_in[1];
    const float* l  = (const float*)d_in[2];
    const float* e  = (const float*)d_in[3];
    const float* w1 = (const float*)d_in[4];
    const float* b1 = (const float*)d_in[5];
    const float* w2 = (const float*)d_in[6];
    const float* b2 = (const float*)d_in[7];
    const float* w3 = (const float*)d_in[8];
    const float* b3 = (const float*)d_in[9];
    const float* w4 = (const float*)d_in[10];
    const float* b4 = (const float*)d_in[11];
    const float* w  = (const float*)d_in[12];
    const float* c  = (const float*)d_in[13];
    const float* g  = (const float*)d_in[14];
    const float* bb = (const float*)d_in[15];

    double* slots = (double*)d_ws;
    float*  zcw   = (float*)((char*)d_ws + ZC_OFF);
    float*  hist  = (float*)((char*)d_ws + HIST_OFF);
    float*  hs    = (float*)((char*)d_ws + HS_OFF);
    float*  outp  = (float*)d_out;

    hipLaunchKernelGGL(mlp_kernel, dim3(2816), dim3(128), 0, stream,
                       bx, w1, b1, w2, b2, c, zcw, slots);

    void* cargs[] = { (void*)&zcw, (void*)&by, (void*)&l, (void*)&e, (void*)&w, (void*)&g, (void*)&bb,
                      (void*)&w3, (void*)&b3, (void*)&w4, (void*)&b4, (void*)&slots, (void*)&outp };
    hipError_t cerr = hipLaunchCooperativeKernel((const void*)scan_coop, dim3(512), dim3(64),
                                                 cargs, 0, stream);
    if (cerr != hipSuccess) {
        (void)hipGetLastError();   // clear sticky error; use proven per-step path
        for (int t = 0; t < TT; ++t) {
            hipLaunchKernelGGL(step_kernel, dim3(256), dim3(128), 0, stream,
                               zcw, l, e, w, g, bb, hist, hs, slots, t);
        }
        hipLaunchKernelGGL(head_kernel, dim3(256), dim3(128), 0, stream,
                           hs, by, g, bb, w3, b3, w4, b4, slots);
        hipLaunchKernelGGL(finalize_kernel, dim3(1), dim3(1), 0, stream, slots, outp);
    }
}

// Round 4
// 424.796 us; speedup vs baseline: 4.6648x; 4.6648x over previous
//
#include <hip/hip_runtime.h>

#define BATCH 32768
#define TT 11
#define EE 128
#define HH 20

// ws layout (bytes):
//   [0 .. 8192)          : double slots[1024]
//       step t stats: slots[t*64 + j]=sum_j, slots[t*64+20+j]=sumsq_j; loss=slots[704], acc=slots[705]
//   [8192 .. +28835840)  : float zc  [T][H][B]
//   [+..]                : float hist[T][H][B]
//   [+..]                : float hs  [H][B]
#define ZC_OFF   8192
#define HIST_OFF (8192 + 28835840)
#define HS_OFF   (8192 + 2*28835840)

__device__ __forceinline__ float waveRed(float v) {
    #pragma unroll
    for (int m = 32; m > 0; m >>= 1) v += __shfl_xor(v, m, 64);
    return v;
}

// ---------------- Kernel A: per-(b,t) input MLP -> zc[t][j][b]; LDS-free ----------------
// f-loop fully unrolled so all register-array indices are static -> no LDS, no scratch.
// Occupancy: thread-capped (16 waves/CU) instead of LDS-capped (12).
__global__ __launch_bounds__(128, 4) void mlp_kernel(
    const float* __restrict__ bx, const float* __restrict__ w1, const float* __restrict__ b1,
    const float* __restrict__ w2, const float* __restrict__ b2,
    const float* __restrict__ c,
    float* __restrict__ zc, double* __restrict__ slots)
{
    const int tid = threadIdx.x;
    if (blockIdx.x == 0) {
        for (int i = tid; i < 1024; i += 128) slots[i] = 0.0;   // later kernels stream-ordered
    }
    const int gid = blockIdx.x * 128 + tid;
    const int t = gid >> 15;
    const int b = gid & (BATCH - 1);
    const float* xp = bx + ((size_t)b * TT + t) * EE;

    // phase 1: s1[50] = relu(x @ w1 + b1); rolled over e4 (only addresses runtime)
    float s1r[50];
    #pragma unroll
    for (int k = 0; k < 50; ++k) s1r[k] = b1[k];
    #pragma unroll 4
    for (int e4 = 0; e4 < 32; ++e4) {
        const float4 xv = *(const float4*)(xp + e4 * 4);
        const float* wr = w1 + e4 * 200;
        #pragma unroll
        for (int k = 0; k < 50; ++k) s1r[k] = fmaf(xv.x, wr[k], s1r[k]);
        #pragma unroll
        for (int k = 0; k < 50; ++k) s1r[k] = fmaf(xv.y, wr[50 + k], s1r[k]);
        #pragma unroll
        for (int k = 0; k < 50; ++k) s1r[k] = fmaf(xv.z, wr[100 + k], s1r[k]);
        #pragma unroll
        for (int k = 0; k < 50; ++k) s1r[k] = fmaf(xv.w, wr[150 + k], s1r[k]);
    }
    #pragma unroll
    for (int k = 0; k < 50; ++k) s1r[k] = fmaxf(s1r[k], 0.f);

    // phases 2+3 fused, c5 rolled (runtime scalar bases), f fully unrolled (static s1r index)
    float zcr[HH];
    #pragma unroll
    for (int j = 0; j < HH; ++j) zcr[j] = 0.f;
    #pragma unroll 1
    for (int c5 = 0; c5 < 5; ++c5) {
        const float* w2c = w2 + c5 * 20;
        const float* b2c = b2 + c5 * 20;
        const float* cc  = c + c5 * 20 * HH;
        float za[20];
        #pragma unroll
        for (int k = 0; k < 20; ++k) za[k] = b2c[k];
        #pragma unroll
        for (int f = 0; f < 50; ++f) {
            const float sv = s1r[f];
            #pragma unroll
            for (int k = 0; k < 20; ++k) za[k] = fmaf(sv, w2c[f * 100 + k], za[k]);
        }
        #pragma unroll
        for (int k = 0; k < 20; ++k) {
            const float zv = fmaxf(za[k], 0.f);
            #pragma unroll
            for (int j = 0; j < HH; ++j) zcr[j] = fmaf(zv, cc[k * HH + j], zcr[j]);
        }
    }
    #pragma unroll
    for (int j = 0; j < HH; ++j) zc[((size_t)(t * HH + j) << 15) + b] = zcr[j];
}

// ---------------- Kernel B (x11): one scan step, 2 lanes per sample ----------------
// 256 blocks x 256 threads = 65536 lanes = 2 per sample. Lane p=tid&1 owns channels [10p,10p+10).
// Cross-half matmul partials and dot products exchanged via shfl_xor(.,1).
__global__ __launch_bounds__(256) void step_kernel(
    const float* __restrict__ zc, const float* __restrict__ lp, const float* __restrict__ ep,
    const float* __restrict__ w, const float* __restrict__ g, const float* __restrict__ bb,
    float* __restrict__ hist, float* __restrict__ hs_buf, double* __restrict__ slots, int t)
{
    __shared__ float red[4][40];
    const int tid = threadIdx.x;
    const int p = tid & 1;                 // half index
    const int sb = tid >> 1;               // sample within block
    const int b = blockIdx.x * 128 + sb;   // 256 blocks * 128 samples
    const int lane = tid & 63, wv = tid >> 6;
    const int jb = 10 * p;                 // my channel base
    const float l0 = lp[0], e0 = ep[0];

    // carry h = BN(hs_{t-1}) for my 10 channels (or 0 at t=0)
    float h[10];
    if (t == 0) {
        #pragma unroll
        for (int jj = 0; jj < 10; ++jj) h[jj] = 0.f;
    } else {
        #pragma unroll
        for (int jj = 0; jj < 10; ++jj) {
            const int j = jb + jj;
            const double s1 = slots[(t - 1) * 64 + j];
            const double s2 = slots[(t - 1) * 64 + HH + j];
            const double mu = s1 * (1.0 / 32768.0);
            const double var = s2 * (1.0 / 32768.0) - mu * mu;
            const float muf = (float)mu;
            const float rsig = 1.0f / sqrtf((float)var);
            const float hv = hs_buf[(j << 15) + b];
            h[jj] = fmaxf(fmaf(g[j] * rsig, hv - muf, bb[j]), 0.f);
        }
    }

    float zct[10];
    #pragma unroll
    for (int jj = 0; jj < 10; ++jj) zct[jj] = zc[((t * HH + jb + jj) << 15) + b];

    // hn = relu(h @ w + zc): po[20] = partials over MY 10 input channels for ALL 20 outputs
    float hn[10];
    {
        float po[20];
        #pragma unroll
        for (int j = 0; j < 20; ++j) {
            float a = 0.f;
            #pragma unroll
            for (int ii = 0; ii < 10; ++ii) a = fmaf(h[ii], w[(jb + ii) * HH + j], a);
            po[j] = a;
        }
        #pragma unroll
        for (int jj = 0; jj < 10; ++jj) {
            const float mine  = p ? po[10 + jj] : po[jj];        // my partial, my channel
            const float send  = p ? po[jj] : po[10 + jj];        // my partial, partner's channel
            const float recv  = __shfl_xor(send, 1, 64);         // partner partial, my channel
            hn[jj] = fmaxf(mine + recv + zct[jj], 0.f);
        }
    }
    #pragma unroll
    for (int jj = 0; jj < 10; ++jj) hist[((t * HH + jb + jj) << 15) + b] = hn[jj];

    // pv = e * sum_{s<=t} l^(t-s) (hn . hn_s) hn_s  (half-dots exchanged)
    float pv[10];
    {
        float dp = 0.f;
        #pragma unroll
        for (int jj = 0; jj < 10; ++jj) dp = fmaf(hn[jj], hn[jj], dp);
        const float d = dp + __shfl_xor(dp, 1, 64);
        const float cd = e0 * d;
        #pragma unroll
        for (int jj = 0; jj < 10; ++jj) pv[jj] = cd * hn[jj];
    }
    float coef = e0 * l0;
    #pragma unroll 1
    for (int s = t - 1; s >= 0; --s) {
        float tv[10];
        #pragma unroll
        for (int jj = 0; jj < 10; ++jj) tv[jj] = hist[((s * HH + jb + jj) << 15) + b];
        float dp = 0.f;
        #pragma unroll
        for (int jj = 0; jj < 10; ++jj) dp = fmaf(hn[jj], tv[jj], dp);
        const float d = dp + __shfl_xor(dp, 1, 64);
        const float cd = coef * d;
        #pragma unroll
        for (int jj = 0; jj < 10; ++jj) pv[jj] = fmaf(cd, tv[jj], pv[jj]);
        coef *= l0;
    }

    // hs = hn @ w + zc + pv (pre-norm; persists to next kernel)
    float hs[10];
    {
        float po[20];
        #pragma unroll
        for (int j = 0; j < 20; ++j) {
            float a = 0.f;
            #pragma unroll
            for (int ii = 0; ii < 10; ++ii) a = fmaf(hn[ii], w[(jb + ii) * HH + j], a);
            po[j] = a;
        }
        #pragma unroll
        for (int jj = 0; jj < 10; ++jj) {
            const float mine = p ? po[10 + jj] : po[jj];
            const float send = p ? po[jj] : po[10 + jj];
            const float recv = __shfl_xor(send, 1, 64);
            hs[jj] = mine + recv + zct[jj] + pv[jj];
            hs_buf[((jb + jj) << 15) + b] = hs[jj];
        }
    }

    // stats: reduce over the wave's 32 samples (lanes sharing bit0), 5 strided hops
    float sm[10], sq[10];
    #pragma unroll
    for (int jj = 0; jj < 10; ++jj) { sm[jj] = hs[jj]; sq[jj] = hs[jj] * hs[jj]; }
    #pragma unroll
    for (int m = 2; m <= 32; m <<= 1) {
        #pragma unroll
        for (int jj = 0; jj < 10; ++jj) {
            sm[jj] += __shfl_xor(sm[jj], m, 64);
            sq[jj] += __shfl_xor(sq[jj], m, 64);
        }
    }
    if (lane < 2) {
        #pragma unroll
        for (int jj = 0; jj < 10; ++jj) {
            red[wv][jb + jj] = sm[jj];
            red[wv][20 + jb + jj] = sq[jj];
        }
    }
    __syncthreads();
    if (tid < 40) {
        atomicAdd(&slots[t * 64 + tid],
                  (double)(red[0][tid] + red[1][tid] + red[2][tid] + red[3][tid]));
    }
}

// ---------------- Kernel C: BN of step 10 + head MLP + loss/acc atomics ----------------
__global__ __launch_bounds__(128) void head_kernel(
    const float* __restrict__ hs_buf, const float* __restrict__ by,
    const float* __restrict__ g, const float* __restrict__ bb,
    const float* __restrict__ w3, const float* __restrict__ b3,
    const float* __restrict__ w4, const float* __restrict__ b4,
    double* __restrict__ slots)
{
    __shared__ float stg[100 * 128];
    __shared__ float red[2][2];
    const int tid = threadIdx.x;
    const int b = blockIdx.x * 128 + tid;
    const int lane = tid & 63, wv = tid >> 6;
    float h[HH];
    #pragma unroll
    for (int j = 0; j < HH; ++j) {
        const double s1 = slots[10 * 64 + j];
        const double s2 = slots[10 * 64 + HH + j];
        const double mu = s1 * (1.0 / 32768.0);
        const double var = s2 * (1.0 / 32768.0) - mu * mu;
        const float muf = (float)mu;
        const float rsig = 1.0f / sqrtf((float)var);
        const float hv = hs_buf[(j << 15) + b];
        h[j] = fmaxf(fmaf(g[j] * rsig, hv - muf, bb[j]), 0.f);
    }
    float hf[100];
    #pragma unroll
    for (int k = 0; k < 100; ++k) hf[k] = b3[k];
    #pragma unroll
    for (int i = 0; i < HH; ++i) {
        const float hv = h[i];
        const float* wr = w3 + i * 100;
        #pragma unroll
        for (int k = 0; k < 100; ++k) hf[k] = fmaf(hv, wr[k], hf[k]);
    }
    #pragma unroll
    for (int k = 0; k < 100; ++k) stg[k * 128 + tid] = fmaxf(hf[k], 0.f);
    float lg[EE];
    #pragma unroll
    for (int e = 0; e < EE; ++e) lg[e] = b4[e];
    for (int k = 0; k < 100; ++k) {
        const float hv = stg[k * 128 + tid];
        const float* wr = w4 + k * EE;
        #pragma unroll
        for (int e = 0; e < EE; ++e) lg[e] = fmaf(hv, wr[e], lg[e]);
    }
    float mx = lg[0]; int am = 0;
    #pragma unroll
    for (int e = 1; e < EE; ++e) { if (lg[e] > mx) { mx = lg[e]; am = e; } }
    float se = 0.f;
    #pragma unroll
    for (int e = 0; e < EE; ++e) se += expf(lg[e] - mx);
    const float lse = logf(se);
    const float* byp = by + (size_t)b * EE;
    float loss = 0.f, bymax = -3.402823e38f; int byam = 0;
    #pragma unroll
    for (int e4 = 0; e4 < 32; ++e4) {
        const float4 v = *(const float4*)(byp + e4 * 4);
        const int e = e4 * 4;
        if (v.x > bymax) { bymax = v.x; byam = e; }
        if (v.y > bymax) { bymax = v.y; byam = e + 1; }
        if (v.z > bymax) { bymax = v.z; byam = e + 2; }
        if (v.w > bymax) { bymax = v.w; byam = e + 3; }
        loss = fmaf(-v.x, lg[e] - mx - lse, loss);
        loss = fmaf(-v.y, lg[e + 1] - mx - lse, loss);
        loss = fmaf(-v.z, lg[e + 2] - mx - lse, loss);
        loss = fmaf(-v.w, lg[e + 3] - mx - lse, loss);
    }
    const float acc_i = (am == byam) ? 1.f : 0.f;
    const float ls = waveRed(loss);
    const float as = waveRed(acc_i);
    if (lane == 0) { red[wv][0] = ls; red[wv][1] = as; }
    __syncthreads();
    if (tid == 0) atomicAdd(&slots[704], (double)(red[0][0] + red[1][0]));
    if (tid == 1) atomicAdd(&slots[705], (double)(red[0][1] + red[1][1]));
}

__global__ void finalize_kernel(const double* __restrict__ slots, float* __restrict__ out) {
    out[0] = (float)(slots[704] * (1.0 / 32768.0));
    out[1] = (float)(slots[705] * (1.0 / 32768.0));
}

extern "C" void kernel_launch(void* const* d_in, const int* in_sizes, int n_in,
                              void* d_out, int out_size, void* d_ws, size_t ws_size,
                              hipStream_t stream) {
    const float* bx = (const float*)d_in[0];
    const float* by = (const float*)d_in[1];
    const float* l  = (const float*)d_in[2];
    const float* e  = (const float*)d_in[3];
    const float* w1 = (const float*)d_in[4];
    const float* b1 = (const float*)d_in[5];
    const float* w2 = (const float*)d_in[6];
    const float* b2 = (const float*)d_in[7];
    const float* w3 = (const float*)d_in[8];
    const float* b3 = (const float*)d_in[9];
    const float* w4 = (const float*)d_in[10];
    const float* b4 = (const float*)d_in[11];
    const float* w  = (const float*)d_in[12];
    const float* c  = (const float*)d_in[13];
    const float* g  = (const float*)d_in[14];
    const float* bb = (const float*)d_in[15];

    double* slots = (double*)d_ws;
    float*  zcw   = (float*)((char*)d_ws + ZC_OFF);
    float*  hist  = (float*)((char*)d_ws + HIST_OFF);
    float*  hs    = (float*)((char*)d_ws + HS_OFF);
    float*  outp  = (float*)d_out;

    hipLaunchKernelGGL(mlp_kernel, dim3(2816), dim3(128), 0, stream,
                       bx, w1, b1, w2, b2, c, zcw, slots);
    for (int t = 0; t < TT; ++t) {
        hipLaunchKernelGGL(step_kernel, dim3(256), dim3(256), 0, stream,
                           zcw, l, e, w, g, bb, hist, hs, slots, t);
    }
    hipLaunchKernelGGL(head_kernel, dim3(256), dim3(128), 0, stream,
                       hs, by, g, bb, w3, b3, w4, b4, slots);
    hipLaunchKernelGGL(finalize_kernel, dim3(1), dim3(1), 0, stream, slots, outp);
}

// Round 5
// 392.141 us; speedup vs baseline: 5.0533x; 1.0833x over previous
//
#include <hip/hip_runtime.h>
#include <hip/hip_bf16.h>

#define BATCH 32768
#define TT 11
#define EE 128
#define HH 20

typedef unsigned short ushort_t;
typedef __attribute__((ext_vector_type(8))) short short8;
typedef __attribute__((ext_vector_type(4))) float f32x4;

// ws layout (bytes):
//   [0 .. 8192)          : double slots[1024]
//   [8192 ..)            : float zc  [T][H][B]   (28835840)
//   [+..]                : float hist[T][H][B]   (28835840)
//   [+..]                : float hs  [H][B]      (2621440)
//   [+..]                : weight fragment region (setup_kernel output)
#define ZC_OFF   8192
#define HIST_OFF (8192 + 28835840)
#define HS_OFF   (8192 + 2*28835840)
#define W1A_OFF  (HS_OFF + 2621440)            // [4kt][4nt][3sp][64][4] u32 = 49152 B
#define W2A_OFF  (W1A_OFF + 49152)             // [2kt][7nt][3sp][64][4] u32 = 43008 B
#define CA_OFF   (W2A_OFF + 43008)             // [4kt][2nt][3sp][64][4] u32 = 24576 B
#define B1F_OFF  (CA_OFF + 24576)              // [4nt][64][4] f32 = 16384 B
#define B2F_OFF  (B1F_OFF + 16384)             // [7nt][64][4] f32 = 28672 B

__device__ __forceinline__ float waveRed(float v) {
    #pragma unroll
    for (int m = 32; m > 0; m >>= 1) v += __shfl_xor(v, m, 64);
    return v;
}

// 3-way bf16 split: v = h1 + h2 + h3 + O(2^-27 v)
__device__ __forceinline__ void split3(float v, ushort_t& a, ushort_t& b, ushort_t& c) {
    __hip_bfloat16 h1 = __float2bfloat16(v);
    float f1 = __bfloat162float(h1);
    float r1 = v - f1;                       // exact (Sterbenz)
    __hip_bfloat16 h2 = __float2bfloat16(r1);
    float f2 = __bfloat162float(h2);
    float r2 = r1 - f2;                      // exact
    __hip_bfloat16 h3 = __float2bfloat16(r2);
    a = *(ushort_t*)&h1; b = *(ushort_t*)&h2; c = *(ushort_t*)&h3;
}

__device__ __forceinline__ f32x4 mfma16(short8 a, short8 b, f32x4 c) {
    return __builtin_amdgcn_mfma_f32_16x16x32_bf16(a, b, c, 0, 0, 0);
}

union FragU { uint4 v; unsigned int u[4]; short8 s; };

// ---------------- setup: pre-fragment weights (A-operand layout) + bias frags + zero slots ----------------
// A-frag layout (16x16x32): lane l: m = l&15, elem j: k = kt*32 + (j>=4?16:0) + 4*(l>>4) + (j&3).
// Stored packed: reg r = elems {2r, 2r+1} as (lo|hi<<16), per split sp.
__global__ __launch_bounds__(256) void setup_kernel(
    const float* __restrict__ w1, const float* __restrict__ b1,
    const float* __restrict__ w2, const float* __restrict__ b2,
    const float* __restrict__ c,
    unsigned int* __restrict__ W1A, unsigned int* __restrict__ W2A, unsigned int* __restrict__ CA,
    float* __restrict__ b1f, float* __restrict__ b2f, double* __restrict__ slots)
{
    const int gid = blockIdx.x * 256 + threadIdx.x;
    const int nth = gridDim.x * 256;
    for (int i = gid; i < 1024; i += nth) slots[i] = 0.0;

    // W1A: A = W1^T  (m = n1 col of w1, k = e row of w1)
    for (int i = gid; i < 4096; i += nth) {
        const int r = i & 3, lane = (i >> 2) & 63, nt = (i >> 8) & 3, kt = i >> 10;
        const int m = nt * 16 + (lane & 15);
        const int g = lane >> 4;
        int j0 = 2 * r, j1 = 2 * r + 1;
        int k0 = kt * 32 + ((j0 >= 4) ? 16 : 0) + 4 * g + (j0 & 3);
        int k1 = kt * 32 + ((j1 >= 4) ? 16 : 0) + 4 * g + (j1 & 3);
        float v0 = (m < 50) ? w1[k0 * 50 + m] : 0.f;
        float v1 = (m < 50) ? w1[k1 * 50 + m] : 0.f;
        ushort_t a0, a1, a2, c0, c1, c2;
        split3(v0, a0, a1, a2); split3(v1, c0, c1, c2);
        W1A[(((kt * 4 + nt) * 3 + 0) * 64 + lane) * 4 + r] = a0 | ((unsigned)c0 << 16);
        W1A[(((kt * 4 + nt) * 3 + 1) * 64 + lane) * 4 + r] = a1 | ((unsigned)c1 << 16);
        W1A[(((kt * 4 + nt) * 3 + 2) * 64 + lane) * 4 + r] = a2 | ((unsigned)c2 << 16);
    }
    // W2A: A = W2^T (m = n2 col of w2 (<100), k = f row (<50))
    for (int i = gid; i < 3584; i += nth) {
        const int r = i & 3, lane = (i >> 2) & 63, rest = i >> 8;
        const int nt = rest % 7, kt = rest / 7;
        const int m = nt * 16 + (lane & 15);
        const int g = lane >> 4;
        int j0 = 2 * r, j1 = 2 * r + 1;
        int k0 = kt * 32 + ((j0 >= 4) ? 16 : 0) + 4 * g + (j0 & 3);
        int k1 = kt * 32 + ((j1 >= 4) ? 16 : 0) + 4 * g + (j1 & 3);
        float v0 = (m < 100 && k0 < 50) ? w2[k0 * 100 + m] : 0.f;
        float v1 = (m < 100 && k1 < 50) ? w2[k1 * 100 + m] : 0.f;
        ushort_t a0, a1, a2, c0, c1, c2;
        split3(v0, a0, a1, a2); split3(v1, c0, c1, c2);
        W2A[(((kt * 7 + nt) * 3 + 0) * 64 + lane) * 4 + r] = a0 | ((unsigned)c0 << 16);
        W2A[(((kt * 7 + nt) * 3 + 1) * 64 + lane) * 4 + r] = a1 | ((unsigned)c1 << 16);
        W2A[(((kt * 7 + nt) * 3 + 2) * 64 + lane) * 4 + r] = a2 | ((unsigned)c2 << 16);
    }
    // CA: A = C^T (m = h col of c (<20), k = q row (<100))
    for (int i = gid; i < 2048; i += nth) {
        const int r = i & 3, lane = (i >> 2) & 63, rest = i >> 8;
        const int nt = rest & 1, kt = rest >> 1;
        const int m = nt * 16 + (lane & 15);
        const int g = lane >> 4;
        int j0 = 2 * r, j1 = 2 * r + 1;
        int k0 = kt * 32 + ((j0 >= 4) ? 16 : 0) + 4 * g + (j0 & 3);
        int k1 = kt * 32 + ((j1 >= 4) ? 16 : 0) + 4 * g + (j1 & 3);
        float v0 = (m < 20 && k0 < 100) ? c[k0 * 20 + m] : 0.f;
        float v1 = (m < 20 && k1 < 100) ? c[k1 * 20 + m] : 0.f;
        ushort_t a0, a1, a2, c0, c1, c2;
        split3(v0, a0, a1, a2); split3(v1, c0, c1, c2);
        CA[(((kt * 2 + nt) * 3 + 0) * 64 + lane) * 4 + r] = a0 | ((unsigned)c0 << 16);
        CA[(((kt * 2 + nt) * 3 + 1) * 64 + lane) * 4 + r] = a1 | ((unsigned)c1 << 16);
        CA[(((kt * 2 + nt) * 3 + 2) * 64 + lane) * 4 + r] = a2 | ((unsigned)c2 << 16);
    }
    // bias frags along the D row-role: n = nt*16 + 4*(lane>>4) + r
    for (int i = gid; i < 1024; i += nth) {
        const int r = i & 3, lane = (i >> 2) & 63, nt = i >> 8;
        const int n = nt * 16 + 4 * (lane >> 4) + r;
        b1f[i] = (n < 50) ? b1[n] : 0.f;
    }
    for (int i = gid; i < 1792; i += nth) {
        const int r = i & 3, lane = (i >> 2) & 63, nt = i >> 8;
        const int n = nt * 16 + 4 * (lane >> 4) + r;
        b2f[i] = (n < 100) ? b2[n] : 0.f;
    }
}

// ---------------- MFMA input MLP: zc^T chain, one 16-row m-tile per wave ----------------
__global__ __launch_bounds__(256) void mlp_mfma(
    const float* __restrict__ bx,
    const unsigned int* __restrict__ W1A, const unsigned int* __restrict__ W2A,
    const unsigned int* __restrict__ CA,
    const float* __restrict__ b1f, const float* __restrict__ b2f,
    float* __restrict__ zc)
{
    __shared__ ushort_t Xs[4][3][2048];     // per-wave, per-split 16x128 bf16, XOR-swizzled (48 KB)
    const int tid = threadIdx.x;
    const int lane = tid & 63, wv = tid >> 6;
    const int R = (blockIdx.x * 4 + wv) * 16;     // 5632 blocks * 64 rows
    const int t = R >> 15;
    const int bbase = R & (BATCH - 1);

    // ---- stage X^T as B-operand source: 3 bf16 splits, swizzle uint2 idx = row*32 + (kblk^row) ----
    {
        const int row = lane >> 2, cg = lane & 3;
        const float4* xp = (const float4*)(bx + ((size_t)(bbase + row) * TT + t) * EE + cg * 32);
        uint2* x0 = (uint2*)Xs[wv][0];
        uint2* x1 = (uint2*)Xs[wv][1];
        uint2* x2 = (uint2*)Xs[wv][2];
        #pragma unroll
        for (int q = 0; q < 8; ++q) {
            const float4 v = xp[q];
            const int idx = row * 32 + ((cg * 8 + q) ^ row);
            ushort_t h0[3], h1[3], h2[3], h3[3];
            split3(v.x, h0[0], h0[1], h0[2]);
            split3(v.y, h1[0], h1[1], h1[2]);
            split3(v.z, h2[0], h2[1], h2[2]);
            split3(v.w, h3[0], h3[1], h3[2]);
            x0[idx] = make_uint2(h0[0] | ((unsigned)h1[0] << 16), h2[0] | ((unsigned)h3[0] << 16));
            x1[idx] = make_uint2(h0[1] | ((unsigned)h1[1] << 16), h2[1] | ((unsigned)h3[1] << 16));
            x2[idx] = make_uint2(h0[2] | ((unsigned)h1[2] << 16), h2[2] | ((unsigned)h3[2] << 16));
        }
    }
    // same-wave DS ordering: compiler inserts lgkmcnt before dependent reads

    const int rrow = lane & 15, g = lane >> 4;
    const uint4* W1A4 = (const uint4*)W1A;
    const uint4* W2A4 = (const uint4*)W2A;
    const uint4* CA4  = (const uint4*)CA;
    const float4* b1f4 = (const float4*)b1f;
    const float4* b2f4 = (const float4*)b2f;

    // ---- Layer 1: D1 = W1^T · X^T  (D1 row-role = n1, col = sample row) ----
    f32x4 D1[4];
    #pragma unroll
    for (int nt = 0; nt < 4; ++nt) D1[nt] = (f32x4){0.f, 0.f, 0.f, 0.f};
    #pragma unroll
    for (int kt = 0; kt < 4; ++kt) {
        FragU B[3];
        #pragma unroll
        for (int sp = 0; sp < 3; ++sp) {
            const uint2* xs = (const uint2*)Xs[wv][sp];
            const int kb = kt * 8 + g;
            uint2 lo = xs[rrow * 32 + (kb ^ rrow)];
            uint2 hi = xs[rrow * 32 + ((kb + 4) ^ rrow)];
            B[sp].u[0] = lo.x; B[sp].u[1] = lo.y; B[sp].u[2] = hi.x; B[sp].u[3] = hi.y;
        }
        #pragma unroll
        for (int nt = 0; nt < 4; ++nt) {
            FragU A0, A1, A2;
            A0.v = W1A4[((kt * 4 + nt) * 3 + 0) * 64 + lane];
            A1.v = W1A4[((kt * 4 + nt) * 3 + 1) * 64 + lane];
            A2.v = W1A4[((kt * 4 + nt) * 3 + 2) * 64 + lane];
            D1[nt] = mfma16(A2.s, B[0].s, D1[nt]);
            D1[nt] = mfma16(A0.s, B[2].s, D1[nt]);
            D1[nt] = mfma16(A1.s, B[1].s, D1[nt]);
            D1[nt] = mfma16(A1.s, B[0].s, D1[nt]);
            D1[nt] = mfma16(A0.s, B[1].s, D1[nt]);
            D1[nt] = mfma16(A0.s, B[0].s, D1[nt]);
        }
    }

    // ---- Layer 2: D2 = W2^T · Z^T ; B2 built in-register from D1 pairs (bias+relu+split) ----
    f32x4 D2[7];
    #pragma unroll
    for (int nt = 0; nt < 7; ++nt) D2[nt] = (f32x4){0.f, 0.f, 0.f, 0.f};
    #pragma unroll
    for (int kt2 = 0; kt2 < 2; ++kt2) {
        FragU B[3];
        #pragma unroll
        for (int half = 0; half < 2; ++half) {
            const int nt = 2 * kt2 + half;
            const float4 bv = b1f4[nt * 64 + lane];
            #pragma unroll
            for (int rp = 0; rp < 2; ++rp) {
                float v0 = fmaxf(D1[nt][2 * rp]     + bv[2 * rp],     0.f);
                float v1 = fmaxf(D1[nt][2 * rp + 1] + bv[2 * rp + 1], 0.f);
                ushort_t s00, s01, s02, s10, s11, s12;
                split3(v0, s00, s01, s02); split3(v1, s10, s11, s12);
                B[0].u[half * 2 + rp] = s00 | ((unsigned)s10 << 16);
                B[1].u[half * 2 + rp] = s01 | ((unsigned)s11 << 16);
                B[2].u[half * 2 + rp] = s02 | ((unsigned)s12 << 16);
            }
        }
        #pragma unroll
        for (int nt2 = 0; nt2 < 7; ++nt2) {
            FragU A0, A1, A2;
            A0.v = W2A4[((kt2 * 7 + nt2) * 3 + 0) * 64 + lane];
            A1.v = W2A4[((kt2 * 7 + nt2) * 3 + 1) * 64 + lane];
            A2.v = W2A4[((kt2 * 7 + nt2) * 3 + 2) * 64 + lane];
            D2[nt2] = mfma16(A2.s, B[0].s, D2[nt2]);
            D2[nt2] = mfma16(A0.s, B[2].s, D2[nt2]);
            D2[nt2] = mfma16(A1.s, B[1].s, D2[nt2]);
            D2[nt2] = mfma16(A1.s, B[0].s, D2[nt2]);
            D2[nt2] = mfma16(A0.s, B[1].s, D2[nt2]);
            D2[nt2] = mfma16(A0.s, B[0].s, D2[nt2]);
        }
    }

    // ---- Layer 3: D3 = C^T · Z2^T ; B3 from D2 pairs; kt3=3 upper half zero ----
    f32x4 D3[2];
    D3[0] = (f32x4){0.f, 0.f, 0.f, 0.f};
    D3[1] = (f32x4){0.f, 0.f, 0.f, 0.f};
    #pragma unroll
    for (int kt3 = 0; kt3 < 4; ++kt3) {
        FragU B[3];
        #pragma unroll
        for (int half = 0; half < 2; ++half) {
            const int nt = 2 * kt3 + half;
            if (nt < 7) {
                const float4 bv = b2f4[nt * 64 + lane];
                #pragma unroll
                for (int rp = 0; rp < 2; ++rp) {
                    float v0 = fmaxf(D2[nt][2 * rp]     + bv[2 * rp],     0.f);
                    float v1 = fmaxf(D2[nt][2 * rp + 1] + bv[2 * rp + 1], 0.f);
                    ushort_t s00, s01, s02, s10, s11, s12;
                    split3(v0, s00, s01, s02); split3(v1, s10, s11, s12);
                    B[0].u[half * 2 + rp] = s00 | ((unsigned)s10 << 16);
                    B[1].u[half * 2 + rp] = s01 | ((unsigned)s11 << 16);
                    B[2].u[half * 2 + rp] = s02 | ((unsigned)s12 << 16);
                }
            } else {
                B[0].u[2] = B[0].u[3] = 0u;
                B[1].u[2] = B[1].u[3] = 0u;
                B[2].u[2] = B[2].u[3] = 0u;
            }
        }
        #pragma unroll
        for (int nt3 = 0; nt3 < 2; ++nt3) {
            FragU A0, A1, A2;
            A0.v = CA4[((kt3 * 2 + nt3) * 3 + 0) * 64 + lane];
            A1.v = CA4[((kt3 * 2 + nt3) * 3 + 1) * 64 + lane];
            A2.v = CA4[((kt3 * 2 + nt3) * 3 + 2) * 64 + lane];
            D3[nt3] = mfma16(A2.s, B[0].s, D3[nt3]);
            D3[nt3] = mfma16(A0.s, B[2].s, D3[nt3]);
            D3[nt3] = mfma16(A1.s, B[1].s, D3[nt3]);
            D3[nt3] = mfma16(A1.s, B[0].s, D3[nt3]);
            D3[nt3] = mfma16(A0.s, B[1].s, D3[nt3]);
            D3[nt3] = mfma16(A0.s, B[0].s, D3[nt3]);
        }
    }

    // ---- store zc (already h-major transposed: row-role = h, col = sample) ----
    const int bcol = bbase + rrow;
    #pragma unroll
    for (int r = 0; r < 4; ++r) {
        const int h = 4 * g + r;
        zc[((size_t)(t * HH + h) << 15) + bcol] = D3[0][r];
    }
    if (g == 0) {
        #pragma unroll
        for (int r = 0; r < 4; ++r) {
            zc[((size_t)(t * HH + 16 + r) << 15) + bcol] = D3[1][r];
        }
    }
}

// ---------------- Kernel B (x11): one scan step, 2 lanes per sample (unchanged, proven) ----------------
__global__ __launch_bounds__(256) void step_kernel(
    const float* __restrict__ zc, const float* __restrict__ lp, const float* __restrict__ ep,
    const float* __restrict__ w, const float* __restrict__ g, const float* __restrict__ bb,
    float* __restrict__ hist, float* __restrict__ hs_buf, double* __restrict__ slots, int t)
{
    __shared__ float red[4][40];
    const int tid = threadIdx.x;
    const int p = tid & 1;
    const int sb = tid >> 1;
    const int b = blockIdx.x * 128 + sb;
    const int lane = tid & 63, wv = tid >> 6;
    const int jb = 10 * p;
    const float l0 = lp[0], e0 = ep[0];

    float h[10];
    if (t == 0) {
        #pragma unroll
        for (int jj = 0; jj < 10; ++jj) h[jj] = 0.f;
    } else {
        #pragma unroll
        for (int jj = 0; jj < 10; ++jj) {
            const int j = jb + jj;
            const double s1 = slots[(t - 1) * 64 + j];
            const double s2 = slots[(t - 1) * 64 + HH + j];
            const double mu = s1 * (1.0 / 32768.0);
            const double var = s2 * (1.0 / 32768.0) - mu * mu;
            const float muf = (float)mu;
            const float rsig = 1.0f / sqrtf((float)var);
            const float hv = hs_buf[(j << 15) + b];
            h[jj] = fmaxf(fmaf(g[j] * rsig, hv - muf, bb[j]), 0.f);
        }
    }

    float zct[10];
    #pragma unroll
    for (int jj = 0; jj < 10; ++jj) zct[jj] = zc[((t * HH + jb + jj) << 15) + b];

    float hn[10];
    {
        float po[20];
        #pragma unroll
        for (int j = 0; j < 20; ++j) {
            float a = 0.f;
            #pragma unroll
            for (int ii = 0; ii < 10; ++ii) a = fmaf(h[ii], w[(jb + ii) * HH + j], a);
            po[j] = a;
        }
        #pragma unroll
        for (int jj = 0; jj < 10; ++jj) {
            const float mine = p ? po[10 + jj] : po[jj];
            const float send = p ? po[jj] : po[10 + jj];
            const float recv = __shfl_xor(send, 1, 64);
            hn[jj] = fmaxf(mine + recv + zct[jj], 0.f);
        }
    }
    #pragma unroll
    for (int jj = 0; jj < 10; ++jj) hist[((t * HH + jb + jj) << 15) + b] = hn[jj];

    float pv[10];
    {
        float dp = 0.f;
        #pragma unroll
        for (int jj = 0; jj < 10; ++jj) dp = fmaf(hn[jj], hn[jj], dp);
        const float d = dp + __shfl_xor(dp, 1, 64);
        const float cd = e0 * d;
        #pragma unroll
        for (int jj = 0; jj < 10; ++jj) pv[jj] = cd * hn[jj];
    }
    float coef = e0 * l0;
    #pragma unroll 1
    for (int s = t - 1; s >= 0; --s) {
        float tv[10];
        #pragma unroll
        for (int jj = 0; jj < 10; ++jj) tv[jj] = hist[((s * HH + jb + jj) << 15) + b];
        float dp = 0.f;
        #pragma unroll
        for (int jj = 0; jj < 10; ++jj) dp = fmaf(hn[jj], tv[jj], dp);
        const float d = dp + __shfl_xor(dp, 1, 64);
        const float cd = coef * d;
        #pragma unroll
        for (int jj = 0; jj < 10; ++jj) pv[jj] = fmaf(cd, tv[jj], pv[jj]);
        coef *= l0;
    }

    float hs[10];
    {
        float po[20];
        #pragma unroll
        for (int j = 0; j < 20; ++j) {
            float a = 0.f;
            #pragma unroll
            for (int ii = 0; ii < 10; ++ii) a = fmaf(hn[ii], w[(jb + ii) * HH + j], a);
            po[j] = a;
        }
        #pragma unroll
        for (int jj = 0; jj < 10; ++jj) {
            const float mine = p ? po[10 + jj] : po[jj];
            const float send = p ? po[jj] : po[10 + jj];
            const float recv = __shfl_xor(send, 1, 64);
            hs[jj] = mine + recv + zct[jj] + pv[jj];
            hs_buf[((jb + jj) << 15) + b] = hs[jj];
        }
    }

    float sm[10], sq[10];
    #pragma unroll
    for (int jj = 0; jj < 10; ++jj) { sm[jj] = hs[jj]; sq[jj] = hs[jj] * hs[jj]; }
    #pragma unroll
    for (int m = 2; m <= 32; m <<= 1) {
        #pragma unroll
        for (int jj = 0; jj < 10; ++jj) {
            sm[jj] += __shfl_xor(sm[jj], m, 64);
            sq[jj] += __shfl_xor(sq[jj], m, 64);
        }
    }
    if (lane < 2) {
        #pragma unroll
        for (int jj = 0; jj < 10; ++jj) {
            red[wv][jb + jj] = sm[jj];
            red[wv][20 + jb + jj] = sq[jj];
        }
    }
    __syncthreads();
    if (tid < 40) {
        atomicAdd(&slots[t * 64 + tid],
                  (double)(red[0][tid] + red[1][tid] + red[2][tid] + red[3][tid]));
    }
}

// ---------------- Kernel C: BN of step 10 + head MLP + loss/acc atomics (unchanged) ----------------
__global__ __launch_bounds__(128) void head_kernel(
    const float* __restrict__ hs_buf, const float* __restrict__ by,
    const float* __restrict__ g, const float* __restrict__ bb,
    const float* __restrict__ w3, const float* __restrict__ b3,
    const float* __restrict__ w4, const float* __restrict__ b4,
    double* __restrict__ slots)
{
    __shared__ float stg[100 * 128];
    __shared__ float red[2][2];
    const int tid = threadIdx.x;
    const int b = blockIdx.x * 128 + tid;
    const int lane = tid & 63, wv = tid >> 6;
    float h[HH];
    #pragma unroll
    for (int j = 0; j < HH; ++j) {
        const double s1 = slots[10 * 64 + j];
        const double s2 = slots[10 * 64 + HH + j];
        const double mu = s1 * (1.0 / 32768.0);
        const double var = s2 * (1.0 / 32768.0) - mu * mu;
        const float muf = (float)mu;
        const float rsig = 1.0f / sqrtf((float)var);
        const float hv = hs_buf[(j << 15) + b];
        h[j] = fmaxf(fmaf(g[j] * rsig, hv - muf, bb[j]), 0.f);
    }
    float hf[100];
    #pragma unroll
    for (int k = 0; k < 100; ++k) hf[k] = b3[k];
    #pragma unroll
    for (int i = 0; i < HH; ++i) {
        const float hv = h[i];
        const float* wr = w3 + i * 100;
        #pragma unroll
        for (int k = 0; k < 100; ++k) hf[k] = fmaf(hv, wr[k], hf[k]);
    }
    #pragma unroll
    for (int k = 0; k < 100; ++k) stg[k * 128 + tid] = fmaxf(hf[k], 0.f);
    float lg[EE];
    #pragma unroll
    for (int e = 0; e < EE; ++e) lg[e] = b4[e];
    for (int k = 0; k < 100; ++k) {
        const float hv = stg[k * 128 + tid];
        const float* wr = w4 + k * EE;
        #pragma unroll
        for (int e = 0; e < EE; ++e) lg[e] = fmaf(hv, wr[e], lg[e]);
    }
    float mx = lg[0]; int am = 0;
    #pragma unroll
    for (int e = 1; e < EE; ++e) { if (lg[e] > mx) { mx = lg[e]; am = e; } }
    float se = 0.f;
    #pragma unroll
    for (int e = 0; e < EE; ++e) se += expf(lg[e] - mx);
    const float lse = logf(se);
    const float* byp = by + (size_t)b * EE;
    float loss = 0.f, bymax = -3.402823e38f; int byam = 0;
    #pragma unroll
    for (int e4 = 0; e4 < 32; ++e4) {
        const float4 v = *(const float4*)(byp + e4 * 4);
        const int e = e4 * 4;
        if (v.x > bymax) { bymax = v.x; byam = e; }
        if (v.y > bymax) { bymax = v.y; byam = e + 1; }
        if (v.z > bymax) { bymax = v.z; byam = e + 2; }
        if (v.w > bymax) { bymax = v.w; byam = e + 3; }
        loss = fmaf(-v.x, lg[e] - mx - lse, loss);
        loss = fmaf(-v.y, lg[e + 1] - mx - lse, loss);
        loss = fmaf(-v.z, lg[e + 2] - mx - lse, loss);
        loss = fmaf(-v.w, lg[e + 3] - mx - lse, loss);
    }
    const float acc_i = (am == byam) ? 1.f : 0.f;
    const float ls = waveRed(loss);
    const float as = waveRed(acc_i);
    if (lane == 0) { red[wv][0] = ls; red[wv][1] = as; }
    __syncthreads();
    if (tid == 0) atomicAdd(&slots[704], (double)(red[0][0] + red[1][0]));
    if (tid == 1) atomicAdd(&slots[705], (double)(red[0][1] + red[1][1]));
}

__global__ void finalize_kernel(const double* __restrict__ slots, float* __restrict__ out) {
    out[0] = (float)(slots[704] * (1.0 / 32768.0));
    out[1] = (float)(slots[705] * (1.0 / 32768.0));
}

extern "C" void kernel_launch(void* const* d_in, const int* in_sizes, int n_in,
                              void* d_out, int out_size, void* d_ws, size_t ws_size,
                              hipStream_t stream) {
    const float* bx = (const float*)d_in[0];
    const float* by = (const float*)d_in[1];
    const float* l  = (const float*)d_in[2];
    const float* e  = (const float*)d_in[3];
    const float* w1 = (const float*)d_in[4];
    const float* b1 = (const float*)d_in[5];
    const float* w2 = (const float*)d_in[6];
    const float* b2 = (const float*)d_in[7];
    const float* w3 = (const float*)d_in[8];
    const float* b3 = (const float*)d_in[9];
    const float* w4 = (const float*)d_in[10];
    const float* b4 = (const float*)d_in[11];
    const float* w  = (const float*)d_in[12];
    const float* c  = (const float*)d_in[13];
    const float* g  = (const float*)d_in[14];
    const float* bb = (const float*)d_in[15];

    double* slots = (double*)d_ws;
    float*  zcw   = (float*)((char*)d_ws + ZC_OFF);
    float*  hist  = (float*)((char*)d_ws + HIST_OFF);
    float*  hs    = (float*)((char*)d_ws + HS_OFF);
    unsigned int* W1A = (unsigned int*)((char*)d_ws + W1A_OFF);
    unsigned int* W2A = (unsigned int*)((char*)d_ws + W2A_OFF);
    unsigned int* CA  = (unsigned int*)((char*)d_ws + CA_OFF);
    float* b1f = (float*)((char*)d_ws + B1F_OFF);
    float* b2f = (float*)((char*)d_ws + B2F_OFF);
    float*  outp  = (float*)d_out;

    hipLaunchKernelGGL(setup_kernel, dim3(16), dim3(256), 0, stream,
                       w1, b1, w2, b2, c, W1A, W2A, CA, b1f, b2f, slots);
    hipLaunchKernelGGL(mlp_mfma, dim3(5632), dim3(256), 0, stream,
                       bx, W1A, W2A, CA, b1f, b2f, zcw);
    for (int t = 0; t < TT; ++t) {
        hipLaunchKernelGGL(step_kernel, dim3(256), dim3(256), 0, stream,
                           zcw, l, e, w, g, bb, hist, hs, slots, t);
    }
    hipLaunchKernelGGL(head_kernel, dim3(256), dim3(128), 0, stream,
                       hs, by, g, bb, w3, b3, w4, b4, slots);
    hipLaunchKernelGGL(finalize_kernel, dim3(1), dim3(1), 0, stream, slots, outp);
}

// Round 6
// 369.294 us; speedup vs baseline: 5.3659x; 1.0619x over previous
//
#include <hip/hip_runtime.h>
#include <hip/hip_bf16.h>

#define BATCH 32768
#define TT 11
#define EE 128
#define HH 20

typedef unsigned short ushort_t;
typedef __attribute__((ext_vector_type(8))) short short8;
typedef __attribute__((ext_vector_type(4))) float f32x4;

// ws layout (bytes):
//   [0 .. 8192)          : double slots[1024]
//   [8192 ..)            : float zc  [T][H][B]   (28835840)
//   [+..]                : float hist[T][H][B]   (28835840)
//   [+..]                : float hs  [H][B]      (2621440)
//   [+..]                : weight fragment region (setup_kernel output)
#define ZC_OFF   8192
#define HIST_OFF (8192 + 28835840)
#define HS_OFF   (8192 + 2*28835840)
#define W1A_OFF  (HS_OFF + 2621440)            // [4kt][4nt][3sp][64][4] u32 = 49152 B
#define W2A_OFF  (W1A_OFF + 49152)             // [2kt][7nt][3sp][64][4] u32 = 43008 B
#define CA_OFF   (W2A_OFF + 43008)             // [4kt][2nt][3sp][64][4] u32 = 24576 B
#define B1F_OFF  (CA_OFF + 24576)              // [4nt][64][4] f32 = 16384 B
#define B2F_OFF  (B1F_OFF + 16384)             // [7nt][64][4] f32 = 28672 B

__device__ __forceinline__ float waveRed(float v) {
    #pragma unroll
    for (int m = 32; m > 0; m >>= 1) v += __shfl_xor(v, m, 64);
    return v;
}

// 3-way bf16 split: v = h1 + h2 + h3 + O(2^-27 v)
__device__ __forceinline__ void split3(float v, ushort_t& a, ushort_t& b, ushort_t& c) {
    __hip_bfloat16 h1 = __float2bfloat16(v);
    float f1 = __bfloat162float(h1);
    float r1 = v - f1;                       // exact (Sterbenz)
    __hip_bfloat16 h2 = __float2bfloat16(r1);
    float f2 = __bfloat162float(h2);
    float r2 = r1 - f2;                      // exact
    __hip_bfloat16 h3 = __float2bfloat16(r2);
    a = *(ushort_t*)&h1; b = *(ushort_t*)&h2; c = *(ushort_t*)&h3;
}

__device__ __forceinline__ f32x4 mfma16(short8 a, short8 b, f32x4 c) {
    return __builtin_amdgcn_mfma_f32_16x16x32_bf16(a, b, c, 0, 0, 0);
}

union FragU { uint4 v; unsigned int u[4]; short8 s; };

// ---------------- setup: pre-fragment weights (A-operand layout) + bias frags + zero slots ----------------
__global__ __launch_bounds__(256) void setup_kernel(
    const float* __restrict__ w1, const float* __restrict__ b1,
    const float* __restrict__ w2, const float* __restrict__ b2,
    const float* __restrict__ c,
    unsigned int* __restrict__ W1A, unsigned int* __restrict__ W2A, unsigned int* __restrict__ CA,
    float* __restrict__ b1f, float* __restrict__ b2f, double* __restrict__ slots)
{
    const int gid = blockIdx.x * 256 + threadIdx.x;
    const int nth = gridDim.x * 256;
    for (int i = gid; i < 1024; i += nth) slots[i] = 0.0;

    for (int i = gid; i < 4096; i += nth) {
        const int r = i & 3, lane = (i >> 2) & 63, nt = (i >> 8) & 3, kt = i >> 10;
        const int m = nt * 16 + (lane & 15);
        const int g = lane >> 4;
        int j0 = 2 * r, j1 = 2 * r + 1;
        int k0 = kt * 32 + ((j0 >= 4) ? 16 : 0) + 4 * g + (j0 & 3);
        int k1 = kt * 32 + ((j1 >= 4) ? 16 : 0) + 4 * g + (j1 & 3);
        float v0 = (m < 50) ? w1[k0 * 50 + m] : 0.f;
        float v1 = (m < 50) ? w1[k1 * 50 + m] : 0.f;
        ushort_t a0, a1, a2, c0, c1, c2;
        split3(v0, a0, a1, a2); split3(v1, c0, c1, c2);
        W1A[(((kt * 4 + nt) * 3 + 0) * 64 + lane) * 4 + r] = a0 | ((unsigned)c0 << 16);
        W1A[(((kt * 4 + nt) * 3 + 1) * 64 + lane) * 4 + r] = a1 | ((unsigned)c1 << 16);
        W1A[(((kt * 4 + nt) * 3 + 2) * 64 + lane) * 4 + r] = a2 | ((unsigned)c2 << 16);
    }
    for (int i = gid; i < 3584; i += nth) {
        const int r = i & 3, lane = (i >> 2) & 63, rest = i >> 8;
        const int nt = rest % 7, kt = rest / 7;
        const int m = nt * 16 + (lane & 15);
        const int g = lane >> 4;
        int j0 = 2 * r, j1 = 2 * r + 1;
        int k0 = kt * 32 + ((j0 >= 4) ? 16 : 0) + 4 * g + (j0 & 3);
        int k1 = kt * 32 + ((j1 >= 4) ? 16 : 0) + 4 * g + (j1 & 3);
        float v0 = (m < 100 && k0 < 50) ? w2[k0 * 100 + m] : 0.f;
        float v1 = (m < 100 && k1 < 50) ? w2[k1 * 100 + m] : 0.f;
        ushort_t a0, a1, a2, c0, c1, c2;
        split3(v0, a0, a1, a2); split3(v1, c0, c1, c2);
        W2A[(((kt * 7 + nt) * 3 + 0) * 64 + lane) * 4 + r] = a0 | ((unsigned)c0 << 16);
        W2A[(((kt * 7 + nt) * 3 + 1) * 64 + lane) * 4 + r] = a1 | ((unsigned)c1 << 16);
        W2A[(((kt * 7 + nt) * 3 + 2) * 64 + lane) * 4 + r] = a2 | ((unsigned)c2 << 16);
    }
    for (int i = gid; i < 2048; i += nth) {
        const int r = i & 3, lane = (i >> 2) & 63, rest = i >> 8;
        const int nt = rest & 1, kt = rest >> 1;
        const int m = nt * 16 + (lane & 15);
        const int g = lane >> 4;
        int j0 = 2 * r, j1 = 2 * r + 1;
        int k0 = kt * 32 + ((j0 >= 4) ? 16 : 0) + 4 * g + (j0 & 3);
        int k1 = kt * 32 + ((j1 >= 4) ? 16 : 0) + 4 * g + (j1 & 3);
        float v0 = (m < 20 && k0 < 100) ? c[k0 * 20 + m] : 0.f;
        float v1 = (m < 20 && k1 < 100) ? c[k1 * 20 + m] : 0.f;
        ushort_t a0, a1, a2, c0, c1, c2;
        split3(v0, a0, a1, a2); split3(v1, c0, c1, c2);
        CA[(((kt * 2 + nt) * 3 + 0) * 64 + lane) * 4 + r] = a0 | ((unsigned)c0 << 16);
        CA[(((kt * 2 + nt) * 3 + 1) * 64 + lane) * 4 + r] = a1 | ((unsigned)c1 << 16);
        CA[(((kt * 2 + nt) * 3 + 2) * 64 + lane) * 4 + r] = a2 | ((unsigned)c2 << 16);
    }
    for (int i = gid; i < 1024; i += nth) {
        const int r = i & 3, lane = (i >> 2) & 63, nt = i >> 8;
        const int n = nt * 16 + 4 * (lane >> 4) + r;
        b1f[i] = (n < 50) ? b1[n] : 0.f;
    }
    for (int i = gid; i < 1792; i += nth) {
        const int r = i & 3, lane = (i >> 2) & 63, nt = i >> 8;
        const int n = nt * 16 + 4 * (lane >> 4) + r;
        b2f[i] = (n < 100) ? b2[n] : 0.f;
    }
}

// ---------------- MFMA input MLP (unchanged, proven exact) ----------------
__global__ __launch_bounds__(256) void mlp_mfma(
    const float* __restrict__ bx,
    const unsigned int* __restrict__ W1A, const unsigned int* __restrict__ W2A,
    const unsigned int* __restrict__ CA,
    const float* __restrict__ b1f, const float* __restrict__ b2f,
    float* __restrict__ zc)
{
    __shared__ ushort_t Xs[4][3][2048];
    const int tid = threadIdx.x;
    const int lane = tid & 63, wv = tid >> 6;
    const int R = (blockIdx.x * 4 + wv) * 16;
    const int t = R >> 15;
    const int bbase = R & (BATCH - 1);

    {
        const int row = lane >> 2, cg = lane & 3;
        const float4* xp = (const float4*)(bx + ((size_t)(bbase + row) * TT + t) * EE + cg * 32);
        uint2* x0 = (uint2*)Xs[wv][0];
        uint2* x1 = (uint2*)Xs[wv][1];
        uint2* x2 = (uint2*)Xs[wv][2];
        #pragma unroll
        for (int q = 0; q < 8; ++q) {
            const float4 v = xp[q];
            const int idx = row * 32 + ((cg * 8 + q) ^ row);
            ushort_t h0[3], h1[3], h2[3], h3[3];
            split3(v.x, h0[0], h0[1], h0[2]);
            split3(v.y, h1[0], h1[1], h1[2]);
            split3(v.z, h2[0], h2[1], h2[2]);
            split3(v.w, h3[0], h3[1], h3[2]);
            x0[idx] = make_uint2(h0[0] | ((unsigned)h1[0] << 16), h2[0] | ((unsigned)h3[0] << 16));
            x1[idx] = make_uint2(h0[1] | ((unsigned)h1[1] << 16), h2[1] | ((unsigned)h3[1] << 16));
            x2[idx] = make_uint2(h0[2] | ((unsigned)h1[2] << 16), h2[2] | ((unsigned)h3[2] << 16));
        }
    }

    const int rrow = lane & 15, g = lane >> 4;
    const uint4* W1A4 = (const uint4*)W1A;
    const uint4* W2A4 = (const uint4*)W2A;
    const uint4* CA4  = (const uint4*)CA;
    const float4* b1f4 = (const float4*)b1f;
    const float4* b2f4 = (const float4*)b2f;

    f32x4 D1[4];
    #pragma unroll
    for (int nt = 0; nt < 4; ++nt) D1[nt] = (f32x4){0.f, 0.f, 0.f, 0.f};
    #pragma unroll
    for (int kt = 0; kt < 4; ++kt) {
        FragU B[3];
        #pragma unroll
        for (int sp = 0; sp < 3; ++sp) {
            const uint2* xs = (const uint2*)Xs[wv][sp];
            const int kb = kt * 8 + g;
            uint2 lo = xs[rrow * 32 + (kb ^ rrow)];
            uint2 hi = xs[rrow * 32 + ((kb + 4) ^ rrow)];
            B[sp].u[0] = lo.x; B[sp].u[1] = lo.y; B[sp].u[2] = hi.x; B[sp].u[3] = hi.y;
        }
        #pragma unroll
        for (int nt = 0; nt < 4; ++nt) {
            FragU A0, A1, A2;
            A0.v = W1A4[((kt * 4 + nt) * 3 + 0) * 64 + lane];
            A1.v = W1A4[((kt * 4 + nt) * 3 + 1) * 64 + lane];
            A2.v = W1A4[((kt * 4 + nt) * 3 + 2) * 64 + lane];
            D1[nt] = mfma16(A2.s, B[0].s, D1[nt]);
            D1[nt] = mfma16(A0.s, B[2].s, D1[nt]);
            D1[nt] = mfma16(A1.s, B[1].s, D1[nt]);
            D1[nt] = mfma16(A1.s, B[0].s, D1[nt]);
            D1[nt] = mfma16(A0.s, B[1].s, D1[nt]);
            D1[nt] = mfma16(A0.s, B[0].s, D1[nt]);
        }
    }

    f32x4 D2[7];
    #pragma unroll
    for (int nt = 0; nt < 7; ++nt) D2[nt] = (f32x4){0.f, 0.f, 0.f, 0.f};
    #pragma unroll
    for (int kt2 = 0; kt2 < 2; ++kt2) {
        FragU B[3];
        #pragma unroll
        for (int half = 0; half < 2; ++half) {
            const int nt = 2 * kt2 + half;
            const float4 bv = b1f4[nt * 64 + lane];
            #pragma unroll
            for (int rp = 0; rp < 2; ++rp) {
                float v0 = fmaxf(D1[nt][2 * rp]     + bv[2 * rp],     0.f);
                float v1 = fmaxf(D1[nt][2 * rp + 1] + bv[2 * rp + 1], 0.f);
                ushort_t s00, s01, s02, s10, s11, s12;
                split3(v0, s00, s01, s02); split3(v1, s10, s11, s12);
                B[0].u[half * 2 + rp] = s00 | ((unsigned)s10 << 16);
                B[1].u[half * 2 + rp] = s01 | ((unsigned)s11 << 16);
                B[2].u[half * 2 + rp] = s02 | ((unsigned)s12 << 16);
            }
        }
        #pragma unroll
        for (int nt2 = 0; nt2 < 7; ++nt2) {
            FragU A0, A1, A2;
            A0.v = W2A4[((kt2 * 7 + nt2) * 3 + 0) * 64 + lane];
            A1.v = W2A4[((kt2 * 7 + nt2) * 3 + 1) * 64 + lane];
            A2.v = W2A4[((kt2 * 7 + nt2) * 3 + 2) * 64 + lane];
            D2[nt2] = mfma16(A2.s, B[0].s, D2[nt2]);
            D2[nt2] = mfma16(A0.s, B[2].s, D2[nt2]);
            D2[nt2] = mfma16(A1.s, B[1].s, D2[nt2]);
            D2[nt2] = mfma16(A1.s, B[0].s, D2[nt2]);
            D2[nt2] = mfma16(A0.s, B[1].s, D2[nt2]);
            D2[nt2] = mfma16(A0.s, B[0].s, D2[nt2]);
        }
    }

    f32x4 D3[2];
    D3[0] = (f32x4){0.f, 0.f, 0.f, 0.f};
    D3[1] = (f32x4){0.f, 0.f, 0.f, 0.f};
    #pragma unroll
    for (int kt3 = 0; kt3 < 4; ++kt3) {
        FragU B[3];
        #pragma unroll
        for (int half = 0; half < 2; ++half) {
            const int nt = 2 * kt3 + half;
            if (nt < 7) {
                const float4 bv = b2f4[nt * 64 + lane];
                #pragma unroll
                for (int rp = 0; rp < 2; ++rp) {
                    float v0 = fmaxf(D2[nt][2 * rp]     + bv[2 * rp],     0.f);
                    float v1 = fmaxf(D2[nt][2 * rp + 1] + bv[2 * rp + 1], 0.f);
                    ushort_t s00, s01, s02, s10, s11, s12;
                    split3(v0, s00, s01, s02); split3(v1, s10, s11, s12);
                    B[0].u[half * 2 + rp] = s00 | ((unsigned)s10 << 16);
                    B[1].u[half * 2 + rp] = s01 | ((unsigned)s11 << 16);
                    B[2].u[half * 2 + rp] = s02 | ((unsigned)s12 << 16);
                }
            } else {
                B[0].u[2] = B[0].u[3] = 0u;
                B[1].u[2] = B[1].u[3] = 0u;
                B[2].u[2] = B[2].u[3] = 0u;
            }
        }
        #pragma unroll
        for (int nt3 = 0; nt3 < 2; ++nt3) {
            FragU A0, A1, A2;
            A0.v = CA4[((kt3 * 2 + nt3) * 3 + 0) * 64 + lane];
            A1.v = CA4[((kt3 * 2 + nt3) * 3 + 1) * 64 + lane];
            A2.v = CA4[((kt3 * 2 + nt3) * 3 + 2) * 64 + lane];
            D3[nt3] = mfma16(A2.s, B[0].s, D3[nt3]);
            D3[nt3] = mfma16(A0.s, B[2].s, D3[nt3]);
            D3[nt3] = mfma16(A1.s, B[1].s, D3[nt3]);
            D3[nt3] = mfma16(A1.s, B[0].s, D3[nt3]);
            D3[nt3] = mfma16(A0.s, B[1].s, D3[nt3]);
            D3[nt3] = mfma16(A0.s, B[0].s, D3[nt3]);
        }
    }

    const int bcol = bbase + rrow;
    #pragma unroll
    for (int r = 0; r < 4; ++r) {
        const int h = 4 * g + r;
        zc[((size_t)(t * HH + h) << 15) + bcol] = D3[0][r];
    }
    if (g == 0) {
        #pragma unroll
        for (int r = 0; r < 4; ++r) {
            zc[((size_t)(t * HH + 16 + r) << 15) + bcol] = D3[1][r];
        }
    }
}

// ---------------- Kernel B (x11): one scan step, 2 lanes per sample (unchanged, proven) ----------------
__global__ __launch_bounds__(256) void step_kernel(
    const float* __restrict__ zc, const float* __restrict__ lp, const float* __restrict__ ep,
    const float* __restrict__ w, const float* __restrict__ g, const float* __restrict__ bb,
    float* __restrict__ hist, float* __restrict__ hs_buf, double* __restrict__ slots, int t)
{
    __shared__ float red[4][40];
    const int tid = threadIdx.x;
    const int p = tid & 1;
    const int sb = tid >> 1;
    const int b = blockIdx.x * 128 + sb;
    const int lane = tid & 63, wv = tid >> 6;
    const int jb = 10 * p;
    const float l0 = lp[0], e0 = ep[0];

    float h[10];
    if (t == 0) {
        #pragma unroll
        for (int jj = 0; jj < 10; ++jj) h[jj] = 0.f;
    } else {
        #pragma unroll
        for (int jj = 0; jj < 10; ++jj) {
            const int j = jb + jj;
            const double s1 = slots[(t - 1) * 64 + j];
            const double s2 = slots[(t - 1) * 64 + HH + j];
            const double mu = s1 * (1.0 / 32768.0);
            const double var = s2 * (1.0 / 32768.0) - mu * mu;
            const float muf = (float)mu;
            const float rsig = 1.0f / sqrtf((float)var);
            const float hv = hs_buf[(j << 15) + b];
            h[jj] = fmaxf(fmaf(g[j] * rsig, hv - muf, bb[j]), 0.f);
        }
    }

    float zct[10];
    #pragma unroll
    for (int jj = 0; jj < 10; ++jj) zct[jj] = zc[((t * HH + jb + jj) << 15) + b];

    float hn[10];
    {
        float po[20];
        #pragma unroll
        for (int j = 0; j < 20; ++j) {
            float a = 0.f;
            #pragma unroll
            for (int ii = 0; ii < 10; ++ii) a = fmaf(h[ii], w[(jb + ii) * HH + j], a);
            po[j] = a;
        }
        #pragma unroll
        for (int jj = 0; jj < 10; ++jj) {
            const float mine = p ? po[10 + jj] : po[jj];
            const float send = p ? po[jj] : po[10 + jj];
            const float recv = __shfl_xor(send, 1, 64);
            hn[jj] = fmaxf(mine + recv + zct[jj], 0.f);
        }
    }
    #pragma unroll
    for (int jj = 0; jj < 10; ++jj) hist[((t * HH + jb + jj) << 15) + b] = hn[jj];

    float pv[10];
    {
        float dp = 0.f;
        #pragma unroll
        for (int jj = 0; jj < 10; ++jj) dp = fmaf(hn[jj], hn[jj], dp);
        const float d = dp + __shfl_xor(dp, 1, 64);
        const float cd = e0 * d;
        #pragma unroll
        for (int jj = 0; jj < 10; ++jj) pv[jj] = cd * hn[jj];
    }
    float coef = e0 * l0;
    #pragma unroll 1
    for (int s = t - 1; s >= 0; --s) {
        float tv[10];
        #pragma unroll
        for (int jj = 0; jj < 10; ++jj) tv[jj] = hist[((s * HH + jb + jj) << 15) + b];
        float dp = 0.f;
        #pragma unroll
        for (int jj = 0; jj < 10; ++jj) dp = fmaf(hn[jj], tv[jj], dp);
        const float d = dp + __shfl_xor(dp, 1, 64);
        const float cd = coef * d;
        #pragma unroll
        for (int jj = 0; jj < 10; ++jj) pv[jj] = fmaf(cd, tv[jj], pv[jj]);
        coef *= l0;
    }

    float hs[10];
    {
        float po[20];
        #pragma unroll
        for (int j = 0; j < 20; ++j) {
            float a = 0.f;
            #pragma unroll
            for (int ii = 0; ii < 10; ++ii) a = fmaf(hn[ii], w[(jb + ii) * HH + j], a);
            po[j] = a;
        }
        #pragma unroll
        for (int jj = 0; jj < 10; ++jj) {
            const float mine = p ? po[10 + jj] : po[jj];
            const float send = p ? po[jj] : po[10 + jj];
            const float recv = __shfl_xor(send, 1, 64);
            hs[jj] = mine + recv + zct[jj] + pv[jj];
            hs_buf[((jb + jj) << 15) + b] = hs[jj];
        }
    }

    float sm[10], sq[10];
    #pragma unroll
    for (int jj = 0; jj < 10; ++jj) { sm[jj] = hs[jj]; sq[jj] = hs[jj] * hs[jj]; }
    #pragma unroll
    for (int m = 2; m <= 32; m <<= 1) {
        #pragma unroll
        for (int jj = 0; jj < 10; ++jj) {
            sm[jj] += __shfl_xor(sm[jj], m, 64);
            sq[jj] += __shfl_xor(sq[jj], m, 64);
        }
    }
    if (lane < 2) {
        #pragma unroll
        for (int jj = 0; jj < 10; ++jj) {
            red[wv][jb + jj] = sm[jj];
            red[wv][20 + jb + jj] = sq[jj];
        }
    }
    __syncthreads();
    if (tid < 40) {
        atomicAdd(&slots[t * 64 + tid],
                  (double)(red[0][tid] + red[1][tid] + red[2][tid] + red[3][tid]));
    }
}

// ---------------- Kernel C v2: head, 4 waves co-operate on 64 samples ----------------
// 512 blocks x 256 threads. Wave p: computes hf features [25p,25p+25) -> LDS (once per sample),
// then logits chunk [32p,32p+32) with online-LSE/argmax partials; parts combined via LDS.
__global__ __launch_bounds__(256, 2) void head_kernel(
    const float* __restrict__ hs_buf, const float* __restrict__ by,
    const float* __restrict__ g, const float* __restrict__ bb,
    const float* __restrict__ w3, const float* __restrict__ b3,
    const float* __restrict__ w4, const float* __restrict__ b4,
    double* __restrict__ slots)
{
    __shared__ float hfs[100][64];                       // 25.6 KB
    __shared__ float cpm[4][64], cps[4][64], cdot[4][64], csby[4][64], cbym[4][64];
    __shared__ int   cidx[4][64], cbyidx[4][64];
    const int tid = threadIdx.x;
    const int lane = tid & 63;     // sample within block
    const int p = tid >> 6;        // part / wave
    const int b = blockIdx.x * 64 + lane;

    // BN of step-10 hs (duplicated across 4 waves; cheap)
    float h[HH];
    #pragma unroll
    for (int j = 0; j < HH; ++j) {
        const double s1 = slots[10 * 64 + j];
        const double s2 = slots[10 * 64 + HH + j];
        const double mu = s1 * (1.0 / 32768.0);
        const double var = s2 * (1.0 / 32768.0) - mu * mu;
        const float muf = (float)mu;
        const float rsig = 1.0f / sqrtf((float)var);
        const float hv = hs_buf[(j << 15) + b];
        h[j] = fmaxf(fmaf(g[j] * rsig, hv - muf, bb[j]), 0.f);
    }

    // hf features [25p, 25p+25): static unroll, uniform w3 s_loads
    #pragma unroll
    for (int k = 0; k < 25; ++k) {
        const int f = p * 25 + k;
        float a = b3[f];
        #pragma unroll
        for (int i = 0; i < HH; ++i) a = fmaf(h[i], w3[i * 100 + f], a);
        hfs[f][lane] = fmaxf(a, 0.f);
    }
    __syncthreads();

    // logits chunk [32]: e = p*32 + u; rolled k-loop (small I-footprint)
    float lg[32];
    {
        const float* b4c = b4 + p * 32;
        #pragma unroll
        for (int u = 0; u < 32; ++u) lg[u] = b4c[u];
    }
    for (int k = 0; k < 100; ++k) {
        const float hv = hfs[k][lane];
        const float* wr = w4 + k * EE + p * 32;          // wave-uniform -> s_load
        #pragma unroll
        for (int u = 0; u < 32; ++u) lg[u] = fmaf(hv, wr[u], lg[u]);
    }

    // part-local first-max argmax + exp-sum
    float pm = lg[0]; int pidx = 0;
    #pragma unroll
    for (int u = 1; u < 32; ++u) { if (lg[u] > pm) { pm = lg[u]; pidx = u; } }
    float ps = 0.f;
    #pragma unroll
    for (int u = 0; u < 32; ++u) ps += expf(lg[u] - pm);

    // by chunk: dot, sum, first-max argmax
    const float* byp = by + (size_t)b * EE + p * 32;
    float dotp = 0.f, sbyp = 0.f, bym = -3.402823e38f; int byi = 0;
    #pragma unroll
    for (int u4 = 0; u4 < 8; ++u4) {
        const float4 v = *(const float4*)(byp + u4 * 4);
        const int u = u4 * 4;
        if (v.x > bym) { bym = v.x; byi = u; }
        if (v.y > bym) { bym = v.y; byi = u + 1; }
        if (v.z > bym) { bym = v.z; byi = u + 2; }
        if (v.w > bym) { bym = v.w; byi = u + 3; }
        dotp = fmaf(v.x, lg[u], dotp);
        dotp = fmaf(v.y, lg[u + 1], dotp);
        dotp = fmaf(v.z, lg[u + 2], dotp);
        dotp = fmaf(v.w, lg[u + 3], dotp);
        sbyp += v.x + v.y + v.z + v.w;
    }

    cpm[p][lane] = pm;  cps[p][lane] = ps;  cdot[p][lane] = dotp;  csby[p][lane] = sbyp;
    cidx[p][lane] = p * 32 + pidx;
    cbym[p][lane] = bym; cbyidx[p][lane] = p * 32 + byi;
    __syncthreads();

    if (p == 0) {
        // combine parts in ascending order (preserves first-occurrence argmax)
        float gm = cpm[0][lane];
        #pragma unroll
        for (int q = 1; q < 4; ++q) gm = fmaxf(gm, cpm[q][lane]);
        float se = 0.f, dot = 0.f, sby = 0.f;
        #pragma unroll
        for (int q = 0; q < 4; ++q) {
            se  += cps[q][lane] * expf(cpm[q][lane] - gm);
            dot += cdot[q][lane];
            sby += csby[q][lane];
        }
        float cm = cpm[0][lane]; int am = cidx[0][lane];
        #pragma unroll
        for (int q = 1; q < 4; ++q) { if (cpm[q][lane] > cm) { cm = cpm[q][lane]; am = cidx[q][lane]; } }
        float bm = cbym[0][lane]; int byam = cbyidx[0][lane];
        #pragma unroll
        for (int q = 1; q < 4; ++q) { if (cbym[q][lane] > bm) { bm = cbym[q][lane]; byam = cbyidx[q][lane]; } }

        const float loss_i = -dot + (gm + logf(se)) * sby;
        const float acc_i = (am == byam) ? 1.f : 0.f;
        const float ls = waveRed(loss_i);
        const float as = waveRed(acc_i);
        if (lane == 0) {
            atomicAdd(&slots[704], (double)ls);
            atomicAdd(&slots[705], (double)as);
        }
    }
}

__global__ void finalize_kernel(const double* __restrict__ slots, float* __restrict__ out) {
    out[0] = (float)(slots[704] * (1.0 / 32768.0));
    out[1] = (float)(slots[705] * (1.0 / 32768.0));
}

extern "C" void kernel_launch(void* const* d_in, const int* in_sizes, int n_in,
                              void* d_out, int out_size, void* d_ws, size_t ws_size,
                              hipStream_t stream) {
    const float* bx = (const float*)d_in[0];
    const float* by = (const float*)d_in[1];
    const float* l  = (const float*)d_in[2];
    const float* e  = (const float*)d_in[3];
    const float* w1 = (const float*)d_in[4];
    const float* b1 = (const float*)d_in[5];
    const float* w2 = (const float*)d_in[6];
    const float* b2 = (const float*)d_in[7];
    const float* w3 = (const float*)d_in[8];
    const float* b3 = (const float*)d_in[9];
    const float* w4 = (const float*)d_in[10];
    const float* b4 = (const float*)d_in[11];
    const float* w  = (const float*)d_in[12];
    const float* c  = (const float*)d_in[13];
    const float* g  = (const float*)d_in[14];
    const float* bb = (const float*)d_in[15];

    double* slots = (double*)d_ws;
    float*  zcw   = (float*)((char*)d_ws + ZC_OFF);
    float*  hist  = (float*)((char*)d_ws + HIST_OFF);
    float*  hs    = (float*)((char*)d_ws + HS_OFF);
    unsigned int* W1A = (unsigned int*)((char*)d_ws + W1A_OFF);
    unsigned int* W2A = (unsigned int*)((char*)d_ws + W2A_OFF);
    unsigned int* CA  = (unsigned int*)((char*)d_ws + CA_OFF);
    float* b1f = (float*)((char*)d_ws + B1F_OFF);
    float* b2f = (float*)((char*)d_ws + B2F_OFF);
    float*  outp  = (float*)d_out;

    hipLaunchKernelGGL(setup_kernel, dim3(16), dim3(256), 0, stream,
                       w1, b1, w2, b2, c, W1A, W2A, CA, b1f, b2f, slots);
    hipLaunchKernelGGL(mlp_mfma, dim3(5632), dim3(256), 0, stream,
                       bx, W1A, W2A, CA, b1f, b2f, zcw);
    for (int t = 0; t < TT; ++t) {
        hipLaunchKernelGGL(step_kernel, dim3(256), dim3(256), 0, stream,
                           zcw, l, e, w, g, bb, hist, hs, slots, t);
    }
    hipLaunchKernelGGL(head_kernel, dim3(512), dim3(256), 0, stream,
                       hs, by, g, bb, w3, b3, w4, b4, slots);
    hipLaunchKernelGGL(finalize_kernel, dim3(1), dim3(1), 0, stream, slots, outp);
}